// Round 5
// baseline (49.509 us; speedup 1.0000x reference)
//
#include <hip/hip_runtime.h>

// Fused: out[b, c*9+d] = sum_hw fcn[b,c,hw] * kern[c*9+d, hw], row-L2-normalized.
// B=4096, C=128, D=9, HW=64, all fp32. One kernel; fcn read once; out written once.
//
// Block = 512 thr = 64 groups x 8 lanes; RB=8 rows/block; grid=512 -> 16 waves/CU.
// Group loops NCH=2 channels. Lane owns 8 hw floats; per-d reduce =
// 2 quad_perm DPP adds (VALU) + 1 ds_swizzle xor-4 (DS) + add. Lane r keeps row r.
// Norm fused: 3 shfl_xor + 8x8 LDS reduce -> rsqrt -> scale -> store.

constexpr int B_TOT = 4096;
constexpr int C_CH  = 128;
constexpr int D_EMB = 9;
constexpr int THREADS = 512;
constexpr int GPB = 64;   // concurrent channels per block
constexpr int NCH = 2;    // channel iterations per group
constexpr int RB  = 8;    // rows per block (= lanes per group)

__device__ __forceinline__ float reduce8_hw(float p) {
    // sum over the 8-lane group: xor1, xor2 via quad_perm DPP (VALU-only)
    p += __int_as_float(__builtin_amdgcn_mov_dpp(__float_as_int(p), 0xB1, 0xf, 0xf, true)); // [1,0,3,2]
    p += __int_as_float(__builtin_amdgcn_mov_dpp(__float_as_int(p), 0x4E, 0xf, 0xf, true)); // [2,3,0,1]
    // xor4 via ds_swizzle BitMode: (4<<10)|0x1F
    p += __int_as_float(__builtin_amdgcn_ds_swizzle(__float_as_int(p), 0x101F));
    return p;
}

__global__ __launch_bounds__(THREADS, 4)
void esenc_fused(const float* __restrict__ fcn,
                 const float* __restrict__ kern,
                 float* __restrict__ out) {
    __shared__ float red[8 * RB];   // 8 waves x 8 rows
    __shared__ float invn[RB];

    const int tid = threadIdx.x;
    const int l   = tid & 7;        // hw-slice lane, later row id
    const int g   = tid >> 3;       // group 0..63
    const int w   = tid >> 6;       // wave 0..7
    const int b0  = blockIdx.x * RB;

    const float4* kern4 = (const float4*)kern;
    const float4* f4    = (const float4*)fcn;

    float keep[NCH][D_EMB];

#pragma unroll
    for (int ch = 0; ch < NCH; ++ch) {
        const int c = ch * GPB + g;

        // kern for this channel: 9 d x 8 floats per lane
        float4 k0[D_EMB], k1[D_EMB];
#pragma unroll
        for (int d = 0; d < D_EMB; ++d) {
            const size_t kb = (size_t)(c * D_EMB + d) * 16;
            k0[d] = kern4[kb + l];
            k1[d] = kern4[kb + 8 + l];
        }

        const size_t fb = ((size_t)b0 * C_CH + c) * 16;
        float4 a0 = f4[fb + l];
        float4 a1 = f4[fb + 8 + l];

#pragma unroll
        for (int r = 0; r < RB; ++r) {
            const float4 c0 = a0, c1 = a1;
            if (r + 1 < RB) {
                const size_t fn = ((size_t)(b0 + r + 1) * C_CH + c) * 16;
                a0 = f4[fn + l];
                a1 = f4[fn + 8 + l];
            }
#pragma unroll
            for (int d = 0; d < D_EMB; ++d) {
                float t;
                t = c0.x * k0[d].x;
                t = fmaf(c0.y, k0[d].y, t);
                t = fmaf(c0.z, k0[d].z, t);
                t = fmaf(c0.w, k0[d].w, t);
                t = fmaf(c1.x, k1[d].x, t);
                t = fmaf(c1.y, k1[d].y, t);
                t = fmaf(c1.z, k1[d].z, t);
                t = fmaf(c1.w, k1[d].w, t);
                t = reduce8_hw(t);
                if (l == r) keep[ch][d] = t;
            }
        }
    }

    // row-norm: per-thread sumsq, reduce over the wave's 8 groups, then 8 waves
    float s = 0.0f;
#pragma unroll
    for (int ch = 0; ch < NCH; ++ch)
#pragma unroll
        for (int d = 0; d < D_EMB; ++d)
            s = fmaf(keep[ch][d], keep[ch][d], s);

    s += __shfl_xor(s, 8,  64);
    s += __shfl_xor(s, 16, 64);
    s += __shfl_xor(s, 32, 64);
    if ((tid & 63) < 8) red[w * RB + l] = s;
    __syncthreads();
    if (tid < RB) {
        float t = 0.0f;
#pragma unroll
        for (int j = 0; j < 8; ++j) t += red[j * RB + tid];
        invn[tid] = 1.0f / sqrtf(t + 1e-10f);
    }
    __syncthreads();
    const float inv = invn[l];

    // lane l owns row b0+l: 2 channels x 9 floats
#pragma unroll
    for (int ch = 0; ch < NCH; ++ch) {
        const int c = ch * GPB + g;
        float* op = out + (size_t)(b0 + l) * (C_CH * D_EMB) + c * D_EMB;
#pragma unroll
        for (int d = 0; d < D_EMB; ++d)
            op[d] = keep[ch][d] * inv;
    }
}

extern "C" void kernel_launch(void* const* d_in, const int* in_sizes, int n_in,
                              void* d_out, int out_size, void* d_ws, size_t ws_size,
                              hipStream_t stream) {
    const float* fcn  = (const float*)d_in[0];   // [4096,128,8,8] f32
    const float* kern = (const float*)d_in[1];   // [1,1152,8,8]  f32
    float* out = (float*)d_out;                  // [4096,1152]   f32

    dim3 grid(B_TOT / RB), block(THREADS);       // 512 blocks
    hipLaunchKernelGGL(esenc_fused, grid, block, 0, stream, fcn, kern, out);
}

// Round 6
// 47.231 us; speedup vs baseline: 1.0482x; 1.0482x over previous
//
#include <hip/hip_runtime.h>

// Fused: out[b, c*9+d] = sum_hw fcn[b,c,hw] * kern[c*9+d, hw], row-L2-normalized.
// B=4096, C=128, D=9, HW=64, all fp32. One kernel; fcn read once; out written once.
//
// Block = 512 thr = 64 groups x 8 lanes; RB=8 rows/block; grid=512.
// launch_bounds(512,2): 2 blocks/CU = 16 waves/CU, 128-VGPR cap (no spill; the
// R5 regression was (512,4) -> 64-VGPR cap -> ~60 spilled regs -> 52MB scratch).
// Group loops NCH=2 channels. Lane owns 8 hw floats; per-d reduce =
// 2 quad_perm DPP adds (VALU) + 1 ds_swizzle xor-4 (DS) + add. Lane r keeps row r.
// Norm fused: 3 shfl_xor + 8x8 LDS reduce -> rsqrt -> scale -> store.

constexpr int B_TOT = 4096;
constexpr int C_CH  = 128;
constexpr int D_EMB = 9;
constexpr int THREADS = 512;
constexpr int GPB = 64;   // concurrent channels per block
constexpr int NCH = 2;    // channel iterations per group
constexpr int RB  = 8;    // rows per block (= lanes per group)

__device__ __forceinline__ float reduce8_hw(float p) {
    // sum over the 8-lane group: xor1, xor2 via quad_perm DPP (VALU-only)
    p += __int_as_float(__builtin_amdgcn_mov_dpp(__float_as_int(p), 0xB1, 0xf, 0xf, true)); // [1,0,3,2]
    p += __int_as_float(__builtin_amdgcn_mov_dpp(__float_as_int(p), 0x4E, 0xf, 0xf, true)); // [2,3,0,1]
    // xor4 via ds_swizzle BitMode: (4<<10)|0x1F
    p += __int_as_float(__builtin_amdgcn_ds_swizzle(__float_as_int(p), 0x101F));
    return p;
}

__global__ __launch_bounds__(THREADS, 2)
void esenc_fused(const float* __restrict__ fcn,
                 const float* __restrict__ kern,
                 float* __restrict__ out) {
    __shared__ float red[8 * RB];   // 8 waves x 8 rows
    __shared__ float invn[RB];

    const int tid = threadIdx.x;
    const int l   = tid & 7;        // hw-slice lane, later row id
    const int g   = tid >> 3;       // group 0..63
    const int w   = tid >> 6;       // wave 0..7
    const int b0  = blockIdx.x * RB;

    const float4* kern4 = (const float4*)kern;
    const float4* f4    = (const float4*)fcn;

    float keep[NCH][D_EMB];

#pragma unroll
    for (int ch = 0; ch < NCH; ++ch) {
        const int c = ch * GPB + g;

        // kern for this channel: 9 d x 8 floats per lane (32-bit indices)
        float4 k0[D_EMB], k1[D_EMB];
#pragma unroll
        for (int d = 0; d < D_EMB; ++d) {
            const unsigned kb = (unsigned)(c * D_EMB + d) * 16u;
            k0[d] = kern4[kb + l];
            k1[d] = kern4[kb + 8u + l];
        }

        const unsigned fb = ((unsigned)b0 * C_CH + (unsigned)c) * 16u;
        float4 a0 = f4[fb + l];
        float4 a1 = f4[fb + 8u + l];

#pragma unroll
        for (int r = 0; r < RB; ++r) {
            const float4 c0 = a0, c1 = a1;
            if (r + 1 < RB) {
                const unsigned fn = fb + (unsigned)(r + 1) * (C_CH * 16u);
                a0 = f4[fn + l];
                a1 = f4[fn + 8u + l];
            }
#pragma unroll
            for (int d = 0; d < D_EMB; ++d) {
                float t;
                t = c0.x * k0[d].x;
                t = fmaf(c0.y, k0[d].y, t);
                t = fmaf(c0.z, k0[d].z, t);
                t = fmaf(c0.w, k0[d].w, t);
                t = fmaf(c1.x, k1[d].x, t);
                t = fmaf(c1.y, k1[d].y, t);
                t = fmaf(c1.z, k1[d].z, t);
                t = fmaf(c1.w, k1[d].w, t);
                t = reduce8_hw(t);
                if (l == r) keep[ch][d] = t;
            }
        }
    }

    // row-norm: per-thread sumsq, reduce over the wave's 8 groups, then 8 waves
    float s = 0.0f;
#pragma unroll
    for (int ch = 0; ch < NCH; ++ch)
#pragma unroll
        for (int d = 0; d < D_EMB; ++d)
            s = fmaf(keep[ch][d], keep[ch][d], s);

    s += __shfl_xor(s, 8,  64);
    s += __shfl_xor(s, 16, 64);
    s += __shfl_xor(s, 32, 64);
    if ((tid & 63) < 8) red[w * RB + l] = s;
    __syncthreads();
    if (tid < RB) {
        float t = 0.0f;
#pragma unroll
        for (int j = 0; j < 8; ++j) t += red[j * RB + tid];
        invn[tid] = 1.0f / sqrtf(t + 1e-10f);
    }
    __syncthreads();
    const float inv = invn[l];

    // lane l owns row b0+l: 2 channels x 9 floats
#pragma unroll
    for (int ch = 0; ch < NCH; ++ch) {
        const int c = ch * GPB + g;
        float* op = out + (size_t)(b0 + l) * (C_CH * D_EMB) + c * D_EMB;
#pragma unroll
        for (int d = 0; d < D_EMB; ++d)
            op[d] = keep[ch][d] * inv;
    }
}

extern "C" void kernel_launch(void* const* d_in, const int* in_sizes, int n_in,
                              void* d_out, int out_size, void* d_ws, size_t ws_size,
                              hipStream_t stream) {
    const float* fcn  = (const float*)d_in[0];   // [4096,128,8,8] f32
    const float* kern = (const float*)d_in[1];   // [1,1152,8,8]  f32
    float* out = (float*)d_out;                  // [4096,1152]   f32

    dim3 grid(B_TOT / RB), block(THREADS);       // 512 blocks
    hipLaunchKernelGGL(esenc_fused, grid, block, 0, stream, fcn, kern, out);
}

// Round 7
// 35.419 us; speedup vs baseline: 1.3978x; 1.3335x over previous
//
#include <hip/hip_runtime.h>

// Fused: out[b, c*9+d] = sum_hw fcn[b,c,hw] * kern[c*9+d, hw], row-L2-normalized.
// B=4096, C=128, D=9, HW=64, all fp32. One kernel; fcn read once; out written once.
//
// R4 structure (best so far, 36.8us): block = 256 thr = 32 groups x 8 lanes,
// RB=8 rows, NCH=4 channel iters, grid 512 (2 blocks/CU, 8 waves/CU).
// Change vs R4: the 8-lane hw-reduce is now PURE VALU (3 DPP adds:
// quad_perm 0xB1 = xor1, quad_perm 0x4E = xor2, row_half_mirror 0x141 = xor4,
// valid because after xor1+xor2 all quad lanes hold the quad-sum).
// R4 paid ~864 ds_bpermute/thread (~17us of DS pipe per CU); now 0 DS in main loop.
// launch_bounds(256,2): 256-VGPR cap >= natural ~170, no spill (R5/R6 lesson).

constexpr int B_TOT = 4096;
constexpr int C_CH  = 128;
constexpr int D_EMB = 9;
constexpr int THREADS = 256;
constexpr int GPB = 32;   // concurrent channels per block
constexpr int NCH = 4;    // channel iterations per group
constexpr int RB  = 8;    // rows per block (= lanes per group)

__device__ __forceinline__ float reduce8_hw(float p) {
    // sum over the 8-lane group, VALU-only DPP
    p += __int_as_float(__builtin_amdgcn_mov_dpp(__float_as_int(p), 0xB1,  0xf, 0xf, true)); // xor1
    p += __int_as_float(__builtin_amdgcn_mov_dpp(__float_as_int(p), 0x4E,  0xf, 0xf, true)); // xor2
    p += __int_as_float(__builtin_amdgcn_mov_dpp(__float_as_int(p), 0x141, 0xf, 0xf, true)); // xor4 (row_half_mirror)
    return p;
}

__global__ __launch_bounds__(THREADS, 2)
void esenc_fused(const float* __restrict__ fcn,
                 const float* __restrict__ kern,
                 float* __restrict__ out) {
    __shared__ float red[4 * RB];   // 4 waves x 8 rows
    __shared__ float invn[RB];

    const int tid = threadIdx.x;
    const int l   = tid & 7;        // hw-slice lane, later row id
    const int g   = tid >> 3;       // group 0..31
    const int w   = tid >> 6;       // wave 0..3
    const int b0  = blockIdx.x * RB;

    const float4* kern4 = (const float4*)kern;
    const float4* f4    = (const float4*)fcn;

    float keep[NCH][D_EMB];

#pragma unroll
    for (int ch = 0; ch < NCH; ++ch) {
        const int c = ch * GPB + g;

        // kern for this channel: 9 d x 8 floats per lane (32-bit indices)
        float4 k0[D_EMB], k1[D_EMB];
#pragma unroll
        for (int d = 0; d < D_EMB; ++d) {
            const unsigned kb = (unsigned)(c * D_EMB + d) * 16u;
            k0[d] = kern4[kb + l];
            k1[d] = kern4[kb + 8u + l];
        }

        const unsigned fb = ((unsigned)b0 * C_CH + (unsigned)c) * 16u;
        float4 a0 = f4[fb + l];
        float4 a1 = f4[fb + 8u + l];

#pragma unroll
        for (int r = 0; r < RB; ++r) {
            const float4 c0 = a0, c1 = a1;
            if (r + 1 < RB) {
                const unsigned fn = fb + (unsigned)(r + 1) * (C_CH * 16u);
                a0 = f4[fn + l];
                a1 = f4[fn + 8u + l];
            }
#pragma unroll
            for (int d = 0; d < D_EMB; ++d) {
                float t;
                t = c0.x * k0[d].x;
                t = fmaf(c0.y, k0[d].y, t);
                t = fmaf(c0.z, k0[d].z, t);
                t = fmaf(c0.w, k0[d].w, t);
                t = fmaf(c1.x, k1[d].x, t);
                t = fmaf(c1.y, k1[d].y, t);
                t = fmaf(c1.z, k1[d].z, t);
                t = fmaf(c1.w, k1[d].w, t);
                t = reduce8_hw(t);
                if (l == r) keep[ch][d] = t;
            }
        }
    }

    // row-norm: per-thread sumsq, reduce over the wave's 8 groups, then 4 waves
    float s = 0.0f;
#pragma unroll
    for (int ch = 0; ch < NCH; ++ch)
#pragma unroll
        for (int d = 0; d < D_EMB; ++d)
            s = fmaf(keep[ch][d], keep[ch][d], s);

    s += __shfl_xor(s, 8,  64);
    s += __shfl_xor(s, 16, 64);
    s += __shfl_xor(s, 32, 64);
    if ((tid & 63) < 8) red[w * RB + l] = s;
    __syncthreads();
    if (tid < RB) {
        float t = red[tid] + red[RB + tid] + red[2 * RB + tid] + red[3 * RB + tid];
        invn[tid] = 1.0f / sqrtf(t + 1e-10f);
    }
    __syncthreads();
    const float inv = invn[l];

    // lane l owns row b0+l: 4 channels x 9 floats
#pragma unroll
    for (int ch = 0; ch < NCH; ++ch) {
        const int c = ch * GPB + g;
        float* op = out + (size_t)(b0 + l) * (C_CH * D_EMB) + c * D_EMB;
#pragma unroll
        for (int d = 0; d < D_EMB; ++d)
            op[d] = keep[ch][d] * inv;
    }
}

extern "C" void kernel_launch(void* const* d_in, const int* in_sizes, int n_in,
                              void* d_out, int out_size, void* d_ws, size_t ws_size,
                              hipStream_t stream) {
    const float* fcn  = (const float*)d_in[0];   // [4096,128,8,8] f32
    const float* kern = (const float*)d_in[1];   // [1,1152,8,8]  f32
    float* out = (float*)d_out;                  // [4096,1152]   f32

    dim3 grid(B_TOT / RB), block(THREADS);       // 512 blocks
    hipLaunchKernelGGL(esenc_fused, grid, block, 0, stream, fcn, kern, out);
}